// Round 4
// baseline (103.498 us; speedup 1.0000x reference)
//
#include <hip/hip_runtime.h>
#include <math.h>

#define NN 4096
#define MM 8
#define BLOCK 256
#define JT 64
#define FOUR_PI_F 12.566370614359172f
#define EPS_F 1e-8f
#define LOG2E_F 1.4426950408889634f

// out[i][m] = sum_j exp(-d_ij/lam_m) / (4*pi*D_m*d_ij) * secretion[j][m]*active[j]
// d_ij = max(sqrt(|p_i-p_j|^2 + eps), r_j)
//
// Math notes:
//  * clamp in squared domain: max(sqrt(d2+eps), r) == sqrt(max(d2+eps, r^2)),
//    and 1/dist == rsqrt(max(d2+eps, r^2)) — one v_rsq replaces v_sqrt+v_rcp.
//  * exp(-d/lam) = exp2(d * na) with na = -log2(e)/lam.
//  * The bench's constants make lam identical for m in {0,1,5}; a wave-uniform
//    runtime check selects a specialized loop sharing one exp2 across those
//    three channels (6 exps/pair instead of 8). Generic path kept for safety.

// Per-j inner tile, templated on the lambda-duplication specialization.
template <bool DUP015>
__device__ __forceinline__ void run_tile(
    const float4* __restrict__ sj, const float4* __restrict__ ss,
    float px, float py, float pz, const float* __restrict__ na,
    float* __restrict__ acc)
{
#pragma unroll 2
    for (int jj = 0; jj < JT; ++jj) {
        const float4 pj = sj[jj];
        const float4 s0 = ss[jj * 2 + 0];
        const float4 s1 = ss[jj * 2 + 1];
        float dx = px - pj.x;
        float dy = py - pj.y;
        float dz = pz - pj.z;
        float d2 = fmaf(dx, dx, fmaf(dy, dy, fmaf(dz, dz, EPS_F)));
        float d2c = fmaxf(d2, pj.w);            // clamp in squared domain
        float rs = __builtin_amdgcn_rsqf(d2c);  // = 1/dist_clamped
        float dcl = d2c * rs;                   // = dist_clamped

        float e[MM];
        if constexpr (DUP015) {
            float e0 = __builtin_amdgcn_exp2f(dcl * na[0]);
            e[0] = e0; e[1] = e0; e[5] = e0;
            e[2] = __builtin_amdgcn_exp2f(dcl * na[2]);
            e[3] = __builtin_amdgcn_exp2f(dcl * na[3]);
            e[4] = __builtin_amdgcn_exp2f(dcl * na[4]);
            e[6] = __builtin_amdgcn_exp2f(dcl * na[6]);
            e[7] = __builtin_amdgcn_exp2f(dcl * na[7]);
        } else {
#pragma unroll
            for (int m = 0; m < MM; ++m)
                e[m] = __builtin_amdgcn_exp2f(dcl * na[m]);
        }

        const float s[MM] = {s0.x, s0.y, s0.z, s0.w, s1.x, s1.y, s1.z, s1.w};
#pragma unroll
        for (int m = 0; m < MM; ++m)
            acc[m] = fmaf(e[m] * rs, s[m], acc[m]);
    }
}

// Partial kernel: grid = (NN/BLOCK, C). Each block owns 256 rows (i) and a
// j-range of NN/C columns, staged through LDS in tiles of JT=64.
// partial[c][i][m] = sum over this block's j-range.
__global__ __launch_bounds__(BLOCK) void diff_partial(
    const float* __restrict__ pos,        // NN x 3
    const float* __restrict__ radius,     // NN
    const float* __restrict__ secretion,  // NN x MM
    const float* __restrict__ Dc,         // MM
    const float* __restrict__ Kd,         // MM
    const int*   __restrict__ active,     // NN (0/1)
    float* __restrict__ partial,          // C x NN x MM
    int jrange)
{
    // Packed LDS: sj[j] = {x, y, z, r^2}; ss[j*2+h] = premultiplied
    // secretion[j][4h..4h+3] * active[j] / (4*pi*D_m). All inner-loop reads
    // are wave-uniform ds_read_b128 broadcasts (no bank conflicts).
    __shared__ float4 sj[JT];
    __shared__ float4 ss[JT * 2];

    const int tid = threadIdx.x;
    const int i = blockIdx.x * BLOCK + tid;
    const int j0base = blockIdx.y * jrange;

    // Per-m constants: na[m] = -log2(e)/lambda_m ; invD[m] = 1/(4*pi*D_m)
    float na[MM], invD[MM], acc[MM];
#pragma unroll
    for (int m = 0; m < MM; ++m) {
        float lam = sqrtf(Dc[m] / Kd[m]);
        na[m] = -LOG2E_F / lam;
        invD[m] = 1.0f / (FOUR_PI_F * Dc[m]);
        acc[m] = 0.0f;
    }
    // Wave-uniform specialization check (see header comment).
    const bool dup015 = (na[0] == na[1]) && (na[0] == na[5]);

    const float px = pos[i * 3 + 0];
    const float py = pos[i * 3 + 1];
    const float pz = pos[i * 3 + 2];

    for (int t = 0; t < jrange; t += JT) {
        const int j0 = j0base + t;
        __syncthreads();  // protect LDS from previous iteration's readers

        // Stage {pos, r^2}: threads 0..63.
        if (tid < JT) {
            int j = j0 + tid;
            float r = radius[j];
            sj[tid] = make_float4(pos[j * 3 + 0], pos[j * 3 + 1],
                                  pos[j * 3 + 2], r * r);
        }
        // Stage premultiplied source: threads 0..127, one float4 each
        // (secretion rows are 32B-aligned; h selects low/high half).
        if (tid < JT * 2) {
            int j = tid >> 1;
            int h = tid & 1;
            const float4 s =
                reinterpret_cast<const float4*>(secretion)[(j0 + j) * 2 + h];
            float a = (active[j0 + j] != 0) ? 1.0f : 0.0f;
            int mb = h * 4;
            ss[tid] = make_float4(s.x * a * invD[mb + 0],
                                  s.y * a * invD[mb + 1],
                                  s.z * a * invD[mb + 2],
                                  s.w * a * invD[mb + 3]);
        }
        __syncthreads();

        if (dup015)
            run_tile<true>(sj, ss, px, py, pz, na, acc);
        else
            run_tile<false>(sj, ss, px, py, pz, na, acc);
    }

    // Write partial sums: thread i writes 8 consecutive floats (2 x float4).
    float4* dst = reinterpret_cast<float4*>(
        partial + (size_t)blockIdx.y * NN * MM + (size_t)i * MM);
    dst[0] = make_float4(acc[0], acc[1], acc[2], acc[3]);
    dst[1] = make_float4(acc[4], acc[5], acc[6], acc[7]);
}

// Reduce over C chunk-slices, vectorized float4: NN*MM/4 = 8192 elements.
__global__ __launch_bounds__(BLOCK) void diff_reduce(
    const float4* __restrict__ partial, float4* __restrict__ out, int C)
{
    int idx = blockIdx.x * BLOCK + threadIdx.x;  // 0 .. NN*MM/4-1
    float4 s = make_float4(0.f, 0.f, 0.f, 0.f);
    for (int c = 0; c < C; ++c) {
        float4 p = partial[(size_t)c * (NN * MM / 4) + idx];
        s.x += p.x; s.y += p.y; s.z += p.z; s.w += p.w;
    }
    out[idx] = s;
}

extern "C" void kernel_launch(void* const* d_in, const int* in_sizes, int n_in,
                              void* d_out, int out_size, void* d_ws, size_t ws_size,
                              hipStream_t stream) {
    const float* pos       = (const float*)d_in[0];
    const float* radius    = (const float*)d_in[1];
    const float* secretion = (const float*)d_in[2];
    const float* Dc        = (const float*)d_in[3];
    const float* Kd        = (const float*)d_in[4];
    const int*   active    = (const int*)d_in[5];
    float* out = (float*)d_out;

    const size_t slice = (size_t)NN * MM * sizeof(float);  // 128 KB per chunk

    int C = 64;
    while (C > 1 && (size_t)C * slice > ws_size) C >>= 1;

    if ((size_t)C * slice <= ws_size) {
        float* partial = (float*)d_ws;
        int jrange = NN / C;
        dim3 grid(NN / BLOCK, C);
        diff_partial<<<grid, BLOCK, 0, stream>>>(pos, radius, secretion, Dc, Kd,
                                                 active, partial, jrange);
        diff_reduce<<<(NN * MM / 4 + BLOCK - 1) / BLOCK, BLOCK, 0, stream>>>(
            (const float4*)partial, (float4*)out, C);
    } else {
        // Workspace too small for even one slice: write directly to out (C=1).
        dim3 grid(NN / BLOCK, 1);
        diff_partial<<<grid, BLOCK, 0, stream>>>(pos, radius, secretion, Dc, Kd,
                                                 active, out, NN);
    }
}

// Round 6
// 95.633 us; speedup vs baseline: 1.0822x; 1.0822x over previous
//
#include <hip/hip_runtime.h>
#include <math.h>

#define NN 4096
#define MM 8
#define BLOCK 256
#define JT 64
#define FOUR_PI_F 12.566370614359172f
#define EPS_F 1e-8f
#define LOG2E_F 1.4426950408889634f

// out[i][m] = sum_j exp(-d_ij/lam_m)/(4*pi*D_m*d_ij) * secretion[j][m]*active[j]
// d_ij = max(sqrt(|p_i-p_j|^2+eps), r_j)
//
// Math/structure notes:
//  * squared-domain clamp: max(sqrt(d2+eps), r) == sqrt(max(d2+eps, r^2));
//    1/dist == rsqrt(...) — one v_rsq replaces v_sqrt+v_rcp.
//  * exp(-d/lam) = exp2(d*na), na = -log2(e)/lam.
//  * ACTIVE COMPACTION: inactive j contribute exactly 0 — staging compacts
//    the tile to active j's via ballot+popcount prefix (order-preserving, so
//    the float sum is bit-identical to the uncompacted loop). ~2x less work
//    for a ~50% active mask; correct for any mask.
//  * lam is bit-identical for m in {0,1,5} with the bench constants; a
//    wave-uniform runtime check picks a loop sharing one exp2 (and one e*rs)
//    across those channels. Generic path kept for arbitrary inputs.

template <bool DUP015>
__device__ __forceinline__ void run_tile(
    int nact, const float4* __restrict__ sj, const float4* __restrict__ ss,
    float px, float py, float pz, const float* __restrict__ na,
    float* __restrict__ acc)
{
#pragma unroll 4
    for (int jj = 0; jj < nact; ++jj) {
        const float4 pj = sj[jj];
        const float4 s0 = ss[jj * 2 + 0];
        const float4 s1 = ss[jj * 2 + 1];
        float dx = px - pj.x;
        float dy = py - pj.y;
        float dz = pz - pj.z;
        float d2 = fmaf(dx, dx, fmaf(dy, dy, fmaf(dz, dz, EPS_F)));
        float d2c = fmaxf(d2, pj.w);            // clamp in squared domain
        float rs = __builtin_amdgcn_rsqf(d2c);  // = 1/dist_clamped
        float dcl = d2c * rs;                   // = dist_clamped

        float ers[MM];  // exp2(dcl*na[m]) * rs, fully unrolled -> registers
        if constexpr (DUP015) {
            float eA = __builtin_amdgcn_exp2f(dcl * na[0]) * rs;
            ers[0] = eA; ers[1] = eA; ers[5] = eA;
            ers[2] = __builtin_amdgcn_exp2f(dcl * na[2]) * rs;
            ers[3] = __builtin_amdgcn_exp2f(dcl * na[3]) * rs;
            ers[4] = __builtin_amdgcn_exp2f(dcl * na[4]) * rs;
            ers[6] = __builtin_amdgcn_exp2f(dcl * na[6]) * rs;
            ers[7] = __builtin_amdgcn_exp2f(dcl * na[7]) * rs;
        } else {
#pragma unroll
            for (int m = 0; m < MM; ++m)
                ers[m] = __builtin_amdgcn_exp2f(dcl * na[m]) * rs;
        }

        const float s[MM] = {s0.x, s0.y, s0.z, s0.w, s1.x, s1.y, s1.z, s1.w};
#pragma unroll
        for (int m = 0; m < MM; ++m)
            acc[m] = fmaf(ers[m], s[m], acc[m]);
    }
}

// Partial kernel: grid = (NN/BLOCK, C). Each block owns 256 rows (i) and a
// j-range of NN/C columns, staged+compacted through LDS in tiles of JT=64.
__global__ __launch_bounds__(BLOCK) void diff_partial(
    const float* __restrict__ pos,        // NN x 3
    const float* __restrict__ radius,     // NN
    const float* __restrict__ secretion,  // NN x MM
    const float* __restrict__ Dc,         // MM
    const float* __restrict__ Kd,         // MM
    const int*   __restrict__ active,     // NN (0/1)
    float* __restrict__ partial,          // C x NN x MM
    int jrange)
{
    // sj[k] = {x,y,z,r^2} of k-th ACTIVE j; ss[k*2+h] = its premultiplied
    // secretion[4h..4h+3] / (4*pi*D_m). Inner reads are uniform broadcasts.
    __shared__ float4 sj[JT];
    __shared__ float4 ss[JT * 2];
    __shared__ int s_nact;

    const int tid = threadIdx.x;
    const int i = blockIdx.x * BLOCK + tid;
    const int j0base = blockIdx.y * jrange;

    float na[MM], invD[MM], acc[MM];
#pragma unroll
    for (int m = 0; m < MM; ++m) {
        float lam = sqrtf(Dc[m] / Kd[m]);
        na[m] = -LOG2E_F / lam;
        invD[m] = 1.0f / (FOUR_PI_F * Dc[m]);
        acc[m] = 0.0f;
    }
    const bool dup015 = (na[0] == na[1]) && (na[0] == na[5]);

    const float px = pos[i * 3 + 0];
    const float py = pos[i * 3 + 1];
    const float pz = pos[i * 3 + 2];

    for (int t = 0; t < jrange; t += JT) {
        const int j0 = j0base + t;
        __syncthreads();  // protect LDS from previous iteration's readers

        // Wave 0 stages + compacts: lane tid owns j0+tid.
        if (tid < JT) {
            const int j = j0 + tid;
            const bool act = (active[j] != 0);
            const unsigned long long mask = __ballot(act);
            if (tid == 0) s_nact = __popcll(mask);
            if (act) {
                const int k = __popcll(mask & ((1ull << tid) - 1ull));
                const float r = radius[j];
                sj[k] = make_float4(pos[j * 3 + 0], pos[j * 3 + 1],
                                    pos[j * 3 + 2], r * r);
                const float4 s0 =
                    reinterpret_cast<const float4*>(secretion)[j * 2 + 0];
                const float4 s1 =
                    reinterpret_cast<const float4*>(secretion)[j * 2 + 1];
                ss[k * 2 + 0] = make_float4(s0.x * invD[0], s0.y * invD[1],
                                            s0.z * invD[2], s0.w * invD[3]);
                ss[k * 2 + 1] = make_float4(s1.x * invD[4], s1.y * invD[5],
                                            s1.z * invD[6], s1.w * invD[7]);
            }
        }
        __syncthreads();

        const int nact = s_nact;
        if (dup015)
            run_tile<true>(nact, sj, ss, px, py, pz, na, acc);
        else
            run_tile<false>(nact, sj, ss, px, py, pz, na, acc);
    }

    float4* dst = reinterpret_cast<float4*>(
        partial + (size_t)blockIdx.y * NN * MM + (size_t)i * MM);
    dst[0] = make_float4(acc[0], acc[1], acc[2], acc[3]);
    dst[1] = make_float4(acc[4], acc[5], acc[6], acc[7]);
}

// Reduce over C chunk-slices, vectorized float4: NN*MM/4 = 8192 elements.
__global__ __launch_bounds__(BLOCK) void diff_reduce(
    const float4* __restrict__ partial, float4* __restrict__ out, int C)
{
    int idx = blockIdx.x * BLOCK + threadIdx.x;
    float4 s = make_float4(0.f, 0.f, 0.f, 0.f);
    for (int c = 0; c < C; ++c) {
        float4 p = partial[(size_t)c * (NN * MM / 4) + idx];
        s.x += p.x; s.y += p.y; s.z += p.z; s.w += p.w;
    }
    out[idx] = s;
}

extern "C" void kernel_launch(void* const* d_in, const int* in_sizes, int n_in,
                              void* d_out, int out_size, void* d_ws, size_t ws_size,
                              hipStream_t stream) {
    const float* pos       = (const float*)d_in[0];
    const float* radius    = (const float*)d_in[1];
    const float* secretion = (const float*)d_in[2];
    const float* Dc        = (const float*)d_in[3];
    const float* Kd        = (const float*)d_in[4];
    const int*   active    = (const int*)d_in[5];
    float* out = (float*)d_out;

    const size_t slice = (size_t)NN * MM * sizeof(float);  // 128 KB per chunk

    int C = 64;
    while (C > 1 && (size_t)C * slice > ws_size) C >>= 1;

    if ((size_t)C * slice <= ws_size) {
        float* partial = (float*)d_ws;
        int jrange = NN / C;
        dim3 grid(NN / BLOCK, C);
        diff_partial<<<grid, BLOCK, 0, stream>>>(pos, radius, secretion, Dc, Kd,
                                                 active, partial, jrange);
        diff_reduce<<<(NN * MM / 4 + BLOCK - 1) / BLOCK, BLOCK, 0, stream>>>(
            (const float4*)partial, (float4*)out, C);
    } else {
        // Workspace too small for even one slice: write directly to out (C=1).
        dim3 grid(NN / BLOCK, 1);
        diff_partial<<<grid, BLOCK, 0, stream>>>(pos, radius, secretion, Dc, Kd,
                                                 active, out, NN);
    }
}